// Round 9
// baseline (65.746 us; speedup 1.0000x reference)
//
#include <hip/hip_runtime.h>

// RaySamplerPDF: per-ray inverse-CDF sampling (NeRF fine sampling).
// R6 core (best: 60.7us) + software-pipelined grid-stride: each wave handles
// 4 ray-pairs; iter i+1's global loads issue before iter i's compute, hiding
// HBM latency under scan+search.
//  - 2 rays per wave (one per 32-lane half); lane sl owns bins 4sl..4sl+3
//    (float4 load, DPP segmented scan, one aligned ds_write_b128; LDS slot
//    j = cdf[j+1]) and samples {sl, sl+32, sl+64, sl+96} (bank-spread search).
//  - Branchless 7-step bit-descent, 4 chains/lane; cb/ca epilogue via
//    ds_read2_b32; 128B-contiguous stores (R8 lesson: never sub-128B chunks).

typedef float f32x4 __attribute__((ext_vector_type(4)));

constexpr int NUM_BINS = 128;
constexpr float EPS_PAD = 1e-5f;
constexpr float INV_S   = 1.0f / 128.0f;
constexpr int ITERS     = 4;               // ray-pairs per wave
constexpr int RPI       = 8;               // rays per block per iter (4 waves x 2)
constexpr int RPB       = RPI * ITERS;     // 32 rays per block

template <int CTRL, int ROW_MASK>
__device__ __forceinline__ float dpp_add(float x) {
    int s = __builtin_amdgcn_update_dpp(0, __float_as_int(x), CTRL, ROW_MASK, 0xf, true);
    return x + __int_as_float(s);
}

__device__ __forceinline__ float rl(float v, int lane) {
    return __int_as_float(__builtin_amdgcn_readlane(__float_as_int(v), lane));
}

__global__ __launch_bounds__(256) void ray_sampler_kernel(
    const float* __restrict__ W,
    const float* __restrict__ U,
    const int*   __restrict__ stratp,
    float*       __restrict__ out)
{
    const int wave = threadIdx.x >> 6;
    const int lane = threadIdx.x & 63;
    const int h    = lane >> 5;          // ray within pair
    const int sl   = lane & 31;          // lane within 32-lane segment

    __shared__ float cdf_s[RPI][NUM_BINS];   // slot j = cdf[j+1]
    float* cw = cdf_s[wave * 2 + h];

    const int strat = *stratp;
    const int b = 4 * sl;

    // iter i ray: blockIdx.x*RPB + i*RPI + wave*2 + h
    size_t rb = ((size_t)blockIdx.x * RPB + wave * 2 + h) * NUM_BINS;
    constexpr size_t RSTEP = (size_t)RPI * NUM_BINS;   // 1024 elems

    // ---- prologue: iter-0 loads ----
    f32x4 w4  = *reinterpret_cast<const f32x4*>(W + rb + b);
    float ur0 = U[rb + sl];
    float ur1 = U[rb + sl + 32];
    float ur2 = U[rb + sl + 64];
    float ur3 = U[rb + sl + 96];

    #pragma unroll
    for (int i = 0; i < ITERS; ++i) {
        // ---- prefetch next iter's inputs (issues before this iter's compute) ----
        f32x4 w4n{};
        float un0 = 0.f, un1 = 0.f, un2 = 0.f, un3 = 0.f;
        const size_t rbn = rb + RSTEP;
        if (i < ITERS - 1) {
            w4n = *reinterpret_cast<const f32x4*>(W + rbn + b);
            un0 = U[rbn + sl];
            un1 = U[rbn + sl + 32];
            un2 = U[rbn + sl + 64];
            un3 = U[rbn + sl + 96];
        }

        // ---- in-lane prefix + 32-lane segmented DPP scan ----
        const float s1 = w4.x;
        const float s2 = s1 + w4.y;
        const float s3 = s2 + w4.z;
        const float quad = s3 + w4.w;

        float incl = quad;
        incl = dpp_add<0x111, 0xf>(incl);   // row_shr:1
        incl = dpp_add<0x112, 0xf>(incl);   // row_shr:2
        incl = dpp_add<0x114, 0xf>(incl);   // row_shr:4
        incl = dpp_add<0x118, 0xf>(incl);   // row_shr:8
        incl = dpp_add<0x142, 0xa>(incl);   // row_bcast:15 (32-lane segments)

        const float totA = rl(incl, 31), totB = rl(incl, 63);
        const float tot  = h ? totB : totA;
        const float padding = fmaxf(EPS_PAD - tot, 0.0f);
        const float ppb     = padding * INV_S;
        const float inv     = __builtin_amdgcn_rcpf(tot + padding);
        const float pre     = incl - quad;

        f32x4 st;                              // slots b..b+3 = cdf[b+1..b+4]
        st.x = (pre + s1   + (float)(b + 1) * ppb) * inv;
        st.y = (pre + s2   + (float)(b + 2) * ppb) * inv;
        st.z = (pre + s3   + (float)(b + 3) * ppb) * inv;
        st.w = (pre + quad + (float)(b + 4) * ppb) * inv;
        *reinterpret_cast<f32x4*>(cw + b) = st;    // aligned ds_write_b128

        // wave-private producer->consumer: drain LDS ops (also orders vs
        // prior iter's reads; DS ops are in-order per wave)
        asm volatile("s_waitcnt lgkmcnt(0)" ::: "memory");

        // ---- stratified uniforms for samples sl, sl+32, sl+64, sl+96 ----
        const float uu0 = strat ? ur0 : 0.5f;
        const float uu1 = strat ? ur1 : 0.5f;
        const float uu2 = strat ? ur2 : 0.5f;
        const float uu3 = strat ? ur3 : 0.5f;
        const float us0 = ((float)(sl)      + uu0) * INV_S;
        const float us1 = ((float)(sl + 32) + uu1) * INV_S;
        const float us2 = ((float)(sl + 64) + uu2) * INV_S;
        const float us3 = ((float)(sl + 96) + uu3) * INV_S;

        // ---- branchless bit-descent: a = last j in [0,127] with cdf[j] <= us ----
        int a0 = 0, a1 = 0, a2 = 0, a3 = 0;
        #pragma unroll
        for (int step = 64; step; step >>= 1) {
            const float c0 = cw[a0 + (step - 1)];
            const float c1 = cw[a1 + (step - 1)];
            const float c2 = cw[a2 + (step - 1)];
            const float c3 = cw[a3 + (step - 1)];
            if (c0 <= us0) a0 += step;
            if (c1 <= us1) a1 += step;
            if (c2 <= us2) a2 += step;
            if (c3 <= us3) a3 += step;
        }

        // ---- epilogue: cb = cdf[a] (slot a-1 | 0), ca = cdf[a+1] (slot a) ----
        const int m0 = a0 ? a0 - 1 : 0;
        const int m1 = a1 ? a1 - 1 : 0;
        const int m2 = a2 ? a2 - 1 : 0;
        const int m3 = a3 ? a3 - 1 : 0;
        const float lo0 = cw[m0], hi0 = cw[m0 + 1];    // ds_read2_b32
        const float lo1 = cw[m1], hi1 = cw[m1 + 1];
        const float lo2 = cw[m2], hi2 = cw[m2 + 1];
        const float lo3 = cw[m3], hi3 = cw[m3 + 1];
        const float cb0 = a0 ? lo0 : 0.0f, ca0 = a0 ? hi0 : lo0;
        const float cb1 = a1 ? lo1 : 0.0f, ca1 = a1 ? hi1 : lo1;
        const float cb2 = a2 ? lo2 : 0.0f, ca2 = a2 ? hi2 : lo2;
        const float cb3 = a3 ? lo3 : 0.0f, ca3 = a3 ? hi3 : lo3;

        float d0 = ca0 - cb0;  d0 = (d0 < 1e-5f) ? 1.0f : d0;
        float d1 = ca1 - cb1;  d1 = (d1 < 1e-5f) ? 1.0f : d1;
        float d2 = ca2 - cb2;  d2 = (d2 < 1e-5f) ? 1.0f : d2;
        float d3 = ca3 - cb3;  d3 = (d3 < 1e-5f) ? 1.0f : d3;

        const float o0 = ((float)a0 + (us0 - cb0) * __builtin_amdgcn_rcpf(d0)) * INV_S;
        const float o1 = ((float)a1 + (us1 - cb1) * __builtin_amdgcn_rcpf(d1)) * INV_S;
        const float o2 = ((float)a2 + (us2 - cb2) * __builtin_amdgcn_rcpf(d2)) * INV_S;
        const float o3 = ((float)a3 + (us3 - cb3) * __builtin_amdgcn_rcpf(d3)) * INV_S;

        // 128B-contiguous per wave-instruction stores
        __builtin_nontemporal_store(o0, out + rb + sl);
        __builtin_nontemporal_store(o1, out + rb + sl + 32);
        __builtin_nontemporal_store(o2, out + rb + sl + 64);
        __builtin_nontemporal_store(o3, out + rb + sl + 96);

        // ---- roll pipeline ----
        if (i < ITERS - 1) {
            w4 = w4n; ur0 = un0; ur1 = un1; ur2 = un2; ur3 = un3;
            rb = rbn;
        }
    }
}

extern "C" void kernel_launch(void* const* d_in, const int* in_sizes, int n_in,
                              void* d_out, int out_size, void* d_ws, size_t ws_size,
                              hipStream_t stream) {
    const float* W     = (const float*)d_in[0];
    const float* U     = (const float*)d_in[1];
    const int*   strat = (const int*)d_in[2];
    float*       out   = (float*)d_out;

    const int num_rays = in_sizes[0] / NUM_BINS;   // 262144
    const int blocks   = num_rays / RPB;           // 8192
    hipLaunchKernelGGL(ray_sampler_kernel, dim3(blocks), dim3(256), 0, stream,
                       W, U, strat, out);
}

// Round 10
// 60.464 us; speedup vs baseline: 1.0874x; 1.0874x over previous
//
#include <hip/hip_runtime.h>

// RaySamplerPDF: per-ray inverse-CDF sampling (NeRF fine sampling).
// 2 rays per wave (one per 32-lane half).
//  - Bins: lane sl owns bins 4sl..4sl+3 (float4 load, DPP segmented scan,
//    one aligned ds_write_b128; LDS slot j holds cdf[j+1], 128 slots/ray).
//  - Samples: lane sl owns samples {sl, sl+32, sl+64, sl+96} so each search
//    chain c targets LDS slot ~ sl+32c -> bank sl: conflict-free at every
//    descent level (upper levels are same-address broadcasts).
// Branchless 7-step bit-descent, 4 independent chains/lane; final cb/ca via
// adjacent-pair LDS read (ds_read2_b32).
//
// BEST CONFIG (60.7us). Tried and REGRESSED: bit-reversed LDS + readlane
// scalarization (R7, 67.4), 4 rays/wave (R8, 65.0 + write amplification),
// software-pipelined grid-stride (R9, 65.7). Aggregate motion 402.6MB/call
// at 60.7us = 6.6 TB/s >= copy ceiling (L3 serves ~50% of input reads).

typedef float f32x4 __attribute__((ext_vector_type(4)));

constexpr int NUM_BINS = 128;
constexpr float EPS_PAD = 1e-5f;
constexpr float INV_S   = 1.0f / 128.0f;
constexpr int RPB       = 8;    // rays per 256-thread block (2 per wave)

template <int CTRL, int ROW_MASK>
__device__ __forceinline__ float dpp_add(float x) {
    int s = __builtin_amdgcn_update_dpp(0, __float_as_int(x), CTRL, ROW_MASK, 0xf, true);
    return x + __int_as_float(s);
}

__global__ __launch_bounds__(256) void ray_sampler_kernel(
    const float* __restrict__ W,
    const float* __restrict__ U,
    const int*   __restrict__ stratp,
    float*       __restrict__ out)
{
    const int wave = threadIdx.x >> 6;
    const int lane = threadIdx.x & 63;
    const int h    = lane >> 5;          // ray within wave
    const int sl   = lane & 31;          // lane within 32-lane segment
    const int ray  = blockIdx.x * RPB + wave * 2 + h;

    // slot j = cdf[j+1]; 128 slots per ray, stride 128 (both halves -> 2/bank = free)
    __shared__ float cdf_s[RPB][NUM_BINS];
    float* cw = cdf_s[wave * 2 + h];

    const size_t rb = (size_t)ray * NUM_BINS;
    const int strat = *stratp;

    // ---- strided sample uniforms (4 x b32, stride-1 across lanes) ----
    const float ur0 = U[rb + sl];
    const float ur1 = U[rb + sl + 32];
    const float ur2 = U[rb + sl + 64];
    const float ur3 = U[rb + sl + 96];

    // ---- weights: contiguous quad per lane ----
    const int b = 4 * sl;
    const f32x4 w4 = *reinterpret_cast<const f32x4*>(W + rb + b);

    const float s1 = w4.x;
    const float s2 = s1 + w4.y;
    const float s3 = s2 + w4.z;
    const float quad = s3 + w4.w;

    // 32-lane segmented inclusive scan of quad sums (DPP, no LDS)
    float incl = quad;
    incl = dpp_add<0x111, 0xf>(incl);   // row_shr:1
    incl = dpp_add<0x112, 0xf>(incl);   // row_shr:2
    incl = dpp_add<0x114, 0xf>(incl);   // row_shr:4
    incl = dpp_add<0x118, 0xf>(incl);   // row_shr:8
    incl = dpp_add<0x142, 0xa>(incl);   // row_bcast:15 (within 32-lane segments)

    const float tot = __shfl(incl, 31 | (lane & 32), 64);   // per-half total
    const float padding = fmaxf(EPS_PAD - tot, 0.0f);
    const float ppb     = padding * INV_S;
    const float inv     = __builtin_amdgcn_rcpf(tot + padding);
    const float pre     = incl - quad;

    f32x4 st;                                      // slots b..b+3 = cdf[b+1..b+4]
    st.x = (pre + s1   + (float)(b + 1) * ppb) * inv;
    st.y = (pre + s2   + (float)(b + 2) * ppb) * inv;
    st.z = (pre + s3   + (float)(b + 3) * ppb) * inv;
    st.w = (pre + quad + (float)(b + 4) * ppb) * inv;
    *reinterpret_cast<f32x4*>(cw + b) = st;        // aligned ds_write_b128

    // wave-private producer->consumer: drain LDS ops, no block barrier needed
    asm volatile("s_waitcnt lgkmcnt(0)" ::: "memory");

    // ---- stratified uniforms for samples sl, sl+32, sl+64, sl+96 ----
    const float uu0 = strat ? ur0 : 0.5f;
    const float uu1 = strat ? ur1 : 0.5f;
    const float uu2 = strat ? ur2 : 0.5f;
    const float uu3 = strat ? ur3 : 0.5f;
    const float us0 = ((float)(sl)      + uu0) * INV_S;
    const float us1 = ((float)(sl + 32) + uu1) * INV_S;
    const float us2 = ((float)(sl + 64) + uu2) * INV_S;
    const float us3 = ((float)(sl + 96) + uu3) * INV_S;

    // ---- bit-descent: a = last j in [0,127] with cdf[j] <= us ----
    // predicate: cdf[a+step] <= us  -> read slot a+step-1 (imm offset step-1)
    int a0 = 0, a1 = 0, a2 = 0, a3 = 0;
    #pragma unroll
    for (int step = 64; step; step >>= 1) {
        const float c0 = cw[a0 + (step - 1)];
        const float c1 = cw[a1 + (step - 1)];
        const float c2 = cw[a2 + (step - 1)];
        const float c3 = cw[a3 + (step - 1)];
        if (c0 <= us0) a0 += step;
        if (c1 <= us1) a1 += step;
        if (c2 <= us2) a2 += step;
        if (c3 <= us3) a3 += step;
    }

    // cb = cdf[a] (slot a-1, or 0 when a==0); ca = cdf[a+1] (slot a)
    const int m0 = a0 ? a0 - 1 : 0;
    const int m1 = a1 ? a1 - 1 : 0;
    const int m2 = a2 ? a2 - 1 : 0;
    const int m3 = a3 ? a3 - 1 : 0;
    const float lo0 = cw[m0], hi0 = cw[m0 + 1];    // fuses to ds_read2_b32
    const float lo1 = cw[m1], hi1 = cw[m1 + 1];
    const float lo2 = cw[m2], hi2 = cw[m2 + 1];
    const float lo3 = cw[m3], hi3 = cw[m3 + 1];
    const float cb0 = a0 ? lo0 : 0.0f, ca0 = a0 ? hi0 : lo0;
    const float cb1 = a1 ? lo1 : 0.0f, ca1 = a1 ? hi1 : lo1;
    const float cb2 = a2 ? lo2 : 0.0f, ca2 = a2 ? hi2 : lo2;
    const float cb3 = a3 ? lo3 : 0.0f, ca3 = a3 ? hi3 : lo3;

    float d0 = ca0 - cb0;  d0 = (d0 < 1e-5f) ? 1.0f : d0;
    float d1 = ca1 - cb1;  d1 = (d1 < 1e-5f) ? 1.0f : d1;
    float d2 = ca2 - cb2;  d2 = (d2 < 1e-5f) ? 1.0f : d2;
    float d3 = ca3 - cb3;  d3 = (d3 < 1e-5f) ? 1.0f : d3;

    const float o0 = ((float)a0 + (us0 - cb0) * __builtin_amdgcn_rcpf(d0)) * INV_S;
    const float o1 = ((float)a1 + (us1 - cb1) * __builtin_amdgcn_rcpf(d1)) * INV_S;
    const float o2 = ((float)a2 + (us2 - cb2) * __builtin_amdgcn_rcpf(d2)) * INV_S;
    const float o3 = ((float)a3 + (us3 - cb3) * __builtin_amdgcn_rcpf(d3)) * INV_S;

    __builtin_nontemporal_store(o0, out + rb + sl);
    __builtin_nontemporal_store(o1, out + rb + sl + 32);
    __builtin_nontemporal_store(o2, out + rb + sl + 64);
    __builtin_nontemporal_store(o3, out + rb + sl + 96);
}

extern "C" void kernel_launch(void* const* d_in, const int* in_sizes, int n_in,
                              void* d_out, int out_size, void* d_ws, size_t ws_size,
                              hipStream_t stream) {
    const float* W     = (const float*)d_in[0];
    const float* U     = (const float*)d_in[1];
    const int*   strat = (const int*)d_in[2];
    float*       out   = (float*)d_out;

    const int num_rays = in_sizes[0] / NUM_BINS;   // 262144
    const int blocks   = num_rays / RPB;           // 32768
    hipLaunchKernelGGL(ray_sampler_kernel, dim3(blocks), dim3(256), 0, stream,
                       W, U, strat, out);
}